// Round 10
// baseline (76.098 us; speedup 1.0000x reference)
//
#include <hip/hip_runtime.h>

// Encoder is dead; LSTM input is constant zero => batch dim uniform. Real
// work: one 512-wide LSTM, 16 serial steps, broadcast 16x4 scalars to
// (16,1024,4). 32 blocks, LLC tagged-slot exchange (tag<<32|float bits,
// parity double-buffered, exact-tag polling; replay-safe with no reset).
// This revision: WAVE-AUTONOMOUS steps. Wave w owns k={16r+2w,16r+2w+1};
// lane=(row rr=4gates x 2k, colchunk cc x 64cols). Per step: matvec ->
// 6 shfl_xor (col reduce + gate gather, all in-register) -> lanes 0-1
// pointwise (hw exp2/rcp) -> publish -> batched 8-slot poll (one vmcnt)
// -> wave-private LDS stage. NO barrier, NO cross-wave LDS in the loop.

#define NWORK  32
#define NTHR   512
#define HID    512
#define TSTEPS 16
#define KPB    16
#define OUTB   16
#define CHS    68     // chbuf chunk stride: 64 + 4 pad (conflict-free reads)

typedef unsigned long long ull;

#define LOG2E  1.44269504f

__device__ __forceinline__ float fexp2(float x) { return __builtin_amdgcn_exp2f(x); }
__device__ __forceinline__ float frcp(float x)  { return __builtin_amdgcn_rcpf(x); }
// sigm(x)=1/(1+e^-x), tanh(x)=1-2/(e^{2x}+1); both saturate correctly.
__device__ __forceinline__ float sigm(float x)  { return frcp(1.0f + fexp2(-LOG2E * x)); }
__device__ __forceinline__ float tanh_f(float x) {
  const float e = fexp2(2.0f * LOG2E * x);
  return 1.0f - 2.0f * frcp(e + 1.0f);
}

// Batched poll: 8 slots at stride 64B, one waitcnt => ~1 LLC RT for all 8.
__device__ __forceinline__ void load8(const ull* base, ull v[8]) {
  asm volatile(
      "global_load_dwordx2 %0, %8, off sc1\n\t"
      "global_load_dwordx2 %1, %8, off offset:64 sc1\n\t"
      "global_load_dwordx2 %2, %8, off offset:128 sc1\n\t"
      "global_load_dwordx2 %3, %8, off offset:192 sc1\n\t"
      "global_load_dwordx2 %4, %8, off offset:256 sc1\n\t"
      "global_load_dwordx2 %5, %8, off offset:320 sc1\n\t"
      "global_load_dwordx2 %6, %8, off offset:384 sc1\n\t"
      "global_load_dwordx2 %7, %8, off offset:448 sc1\n\t"
      "s_waitcnt vmcnt(0)"
      : "=&v"(v[0]), "=&v"(v[1]), "=&v"(v[2]), "=&v"(v[3]),
        "=&v"(v[4]), "=&v"(v[5]), "=&v"(v[6]), "=&v"(v[7])
      : "v"(base)
      : "memory");
}

__global__ __launch_bounds__(NTHR, 2) void lstm_seq_kernel(
    const float* __restrict__ Whh,
    const float* __restrict__ bih,
    const float* __restrict__ bhh,
    const float* __restrict__ Wo,
    const float* __restrict__ bo,
    float* __restrict__ out,
    ull* __restrict__ slots)   // [2][512] tagged slots, device-coherent
{
  const int tid = threadIdx.x;
  const int r_  = (int)blockIdx.x;       // rank: owns k in [16r, 16r+16)
  const int w   = tid >> 6;              // wave 0..7
  const int l   = tid & 63;
  const int rr  = l & 7;                 // row-in-wave: 4 gates x 2 k's
  const int cc  = l >> 3;                // col chunk (64 cols)
  const int gate = rr >> 1, kloc = rr & 1;
  const int kown = r_ * KPB + w * 2 + kloc;
  const int grow = gate * HID + kown;    // this lane's gate-row of Whh

  __shared__ float chbuf[8][8 * CHS];    // per-wave h, padded chunks
  __shared__ float hstash[HID];          // h_{r+1} for this block's out row
  __shared__ float vals[4];

  // ---- weights: 64-col slice of one gate-row per lane (64 VGPRs) ----
  float4 wreg[16];
  {
    const float4* Wr = reinterpret_cast<const float4*>(
        Whh + (size_t)grow * HID + cc * 64);
#pragma unroll
    for (int j = 0; j < 16; ++j) wreg[j] = Wr[j];
  }

  // ---- h1 = f(bias) for column tid (h0==0 kills the recurrent term) ----
  {
    const float gi = bih[tid]           + bhh[tid];
    const float gf = bih[HID + tid]     + bhh[HID + tid];
    const float gg = bih[2*HID + tid]   + bhh[2*HID + tid];
    const float go = bih[3*HID + tid]   + bhh[3*HID + tid];
    const float c1 = sigm(gf) * 0.0f + sigm(gi) * tanh_f(gg);
    hstash[tid] = sigm(go) * tanh_f(c1);
  }

  // ---- owner lanes (l<2): bias sums + c1 for k = 16r + 2w + l ----
  float c_state = 0.0f;
  float bs_i = 0.f, bs_f = 0.f, bs_g = 0.f, bs_o = 0.f;
  if (l < 2) {
    const int k = r_ * KPB + w * 2 + l;
    bs_i = bih[k]           + bhh[k];
    bs_f = bih[HID + k]     + bhh[HID + k];
    bs_g = bih[2*HID + k]   + bhh[2*HID + k];
    bs_o = bih[3*HID + k]   + bhh[3*HID + k];
    c_state = sigm(bs_f) * 0.0f + sigm(bs_i) * tanh_f(bs_g);
  }

  __syncthreads();   // hstash (=h1) complete
  // stage h1 into this wave's chbuf slice (positions cc*CHS + rr + 8m)
#pragma unroll
  for (int m = 0; m < 8; ++m)
    chbuf[w][cc * CHS + rr + 8 * m] = hstash[cc * 64 + rr + 8 * m];
  __syncthreads();   // all waves staged; hstash may be overwritten later
  // (rank 0 keeps hstash = h1 for its output row)

  const ull* base0 = slots + (cc * 64 + rr);   // parity-0 poll base
  const ull* base1 = base0 + HID;              // parity-1 poll base

  // ---- steps 2..16: matvec -> shfl reduce -> pointwise -> publish -> poll ----
  for (int s = 2; s <= TSTEPS; ++s) {
    const int p = s & 1;

    float4 a = make_float4(0.f, 0.f, 0.f, 0.f);
    {
      const float4* hq = reinterpret_cast<const float4*>(&chbuf[w][cc * CHS]);
#pragma unroll
      for (int j = 0; j < 16; ++j) {
        const float4 h4 = hq[j];   // 8 distinct addrs/instr, pad => no conflict
        a.x = fmaf(wreg[j].x, h4.x, a.x);
        a.y = fmaf(wreg[j].y, h4.y, a.y);
        a.z = fmaf(wreg[j].z, h4.z, a.z);
        a.w = fmaf(wreg[j].w, h4.w, a.w);
      }
    }
    float d = (a.x + a.y) + (a.z + a.w);
    d += __shfl_xor(d, 8);           // reduce over the 8 col-chunk lanes
    d += __shfl_xor(d, 16);
    d += __shfl_xor(d, 32);
    const float dx2 = __shfl_xor(d, 2);   // other gates of this k
    const float dx4 = __shfl_xor(d, 4);
    const float dx6 = __shfl_xor(d, 6);

    if (l < 2) {   // lane l: rr=l => gate0(i); dx2=f, dx4=g, dx6=o
      const float gi = d   + bs_i;
      const float gf = dx2 + bs_f;
      const float gg = dx4 + bs_g;
      const float go = dx6 + bs_o;
      c_state = sigm(gf) * c_state + sigm(gi) * tanh_f(gg);
      const float hv = sigm(go) * tanh_f(c_state);
      const ull pk = ((ull)(unsigned)s << 32) | (ull)__float_as_uint(hv);
      __hip_atomic_store(slots + p * HID + r_ * KPB + w * 2 + l, pk,
                         __ATOMIC_RELAXED, __HIP_MEMORY_SCOPE_AGENT);
    }

    if (s < TSTEPS) {
      // poll this lane's 8 slots (h[cc*64 + rr + 8m]) for tag s, batched
      const ull* bp = p ? base1 : base0;
      ull v[8];
      for (;;) {
        load8(bp, v);
        bool ok = true;
#pragma unroll
        for (int m = 0; m < 8; ++m)
          ok = ok && ((unsigned)(v[m] >> 32) == (unsigned)s);
        if (ok) break;
      }
#pragma unroll
      for (int m = 0; m < 8; ++m)
        chbuf[w][cc * CHS + rr + 8 * m] = __uint_as_float((unsigned)v[m]);
      if (r_ >= 1 && r_ < OUTB - 1 && s == r_ + 1) {   // capture h_{r+1}
#pragma unroll
        for (int m = 0; m < 8; ++m)
          hstash[cc * 64 + rr + 8 * m] = __uint_as_float((unsigned)v[m]);
      }
      asm volatile("s_waitcnt lgkmcnt(0)" ::: "memory");
      __builtin_amdgcn_sched_barrier(0);
    }
  }

  if (r_ >= OUTB) return;   // ranks 16..31 only feed the recurrence

  if (r_ == OUTB - 1) {     // h_16 (tag 16, parity 0) never staged in-loop
    const ull* pp = slots + tid;
    ull v;
    do {
      v = __hip_atomic_load(pp, __ATOMIC_RELAXED, __HIP_MEMORY_SCOPE_AGENT);
    } while ((unsigned)(v >> 32) != (unsigned)TSTEPS);
    hstash[tid] = __uint_as_float((unsigned)v);
  }
  __syncthreads();   // hstash (= h_{r+1}) complete for the epilogue

  // ---- output row t = r: 4 dot products of length 512, then broadcast ----
  if (tid < 256) {
    const int wo = tid >> 6;  // output dim 0..3 (one wave each)
    const int ll = tid & 63;
    float sacc = 0.0f;
#pragma unroll
    for (int j = 0; j < 8; ++j) {
      const int k2 = ll + 64 * j;
      sacc = fmaf(Wo[wo * HID + k2], hstash[k2], sacc);
    }
#pragma unroll
    for (int m = 32; m > 0; m >>= 1) sacc += __shfl_xor(sacc, m);
    if (ll == 0) vals[wo] = sacc + bo[wo];
  }
  __syncthreads();

  const float4 vv = make_float4(vals[0], vals[1], vals[2], vals[3]);
  float4* out4 = reinterpret_cast<float4*>(out) + (size_t)r_ * 1024;
  out4[tid]       = vv;   // row t=r : 1024 batch rows x 4 floats
  out4[tid + 512] = vv;
}

extern "C" void kernel_launch(void* const* d_in, const int* in_sizes, int n_in,
                              void* d_out, int out_size, void* d_ws, size_t ws_size,
                              hipStream_t stream) {
  // setup_inputs() order:
  // 0 images, 1 W1, 2 b1, 3 W2, 4 b2, 5 W3, 6 b3, 7 We, 8 be,
  // 9 Wih, 10 Whh, 11 bih, 12 bhh, 13 Wg, 14 bg, 15 Wk, 16 bk,
  // 17 Wo, 18 bo, 19 Wc, 20 bc
  const float* Whh = (const float*)d_in[10];
  const float* bih = (const float*)d_in[11];
  const float* bhh = (const float*)d_in[12];
  const float* Wo  = (const float*)d_in[17];
  const float* bo  = (const float*)d_in[18];
  float* out = (float*)d_out;

  // 8 KB of tagged slots. No reset needed: published values are
  // replay-invariant (stale tag==fresh tag implies identical bits), and the
  // 0xAAAAAAAA poison tag never matches tags 2..16.
  ull* slots;
  if (d_ws != nullptr && ws_size >= 2 * HID * sizeof(ull)) {
    slots = (ull*)d_ws;
  } else {
    // Out-tail fallback: region inside rank-15's own output row; rank 15
    // reads all slots strictly before overwriting it.
    slots = (ull*)(out + (size_t)out_size) - 2 * HID;
  }

  lstm_seq_kernel<<<dim3(NWORK), dim3(NTHR), 0, stream>>>(
      Whh, bih, bhh, Wo, bo, out, slots);
}

// Round 11
// 31.442 us; speedup vs baseline: 2.4203x; 2.4203x over previous
//
#include <hip/hip_runtime.h>

// Encoder is dead; LSTM input is constant zero => batch dim uniform. Real
// work: one 512-wide LSTM, 16 serial steps, broadcast 16x4 scalars to
// (16,1024,4). R6 skeleton (proven 33us): 32 workers at blockIdx%8==0 of a
// 256-block grid, lane-owns-slot tagged exchange (tag<<32|float), sequential
// sc0->LLC poll, sc0+agent publish, one barrier/step, parity-buffered gpT.
// This revision grafts ONLY the two isolated-good pieces onto it:
//  (1) h1 = f(bias) computed locally (h0==0) -- removes one exchange hop and
//      makes the prologue barrier-free (R7's good half).
//  (2) hardware exp2/rcp activations -- cuts the serial publish chain
//      ~400cy -> ~150cy per step (R8's good half).

#define NTHR   512
#define HID    512
#define TSTEPS 16
#define KPB    16      // k's per worker block
#define OUTB   16      // ranks that write output rows
#define NWORK  32

typedef unsigned long long ull;

#define LOG2E  1.44269504f

__device__ __forceinline__ float fexp2(float x) { return __builtin_amdgcn_exp2f(x); }
__device__ __forceinline__ float frcp(float x)  { return __builtin_amdgcn_rcpf(x); }
// sigm(x)=1/(1+e^-x): x->-inf => rcp(inf)=0; x->+inf => 1. Correct saturation.
__device__ __forceinline__ float sigm(float x)  { return frcp(1.0f + fexp2(-LOG2E * x)); }
// tanh(x)=1-2/(e^{2x}+1): x->+inf => 1; x->-inf => -1. Correct saturation.
__device__ __forceinline__ float tanh_f(float x) {
  const float e = fexp2(2.0f * LOG2E * x);
  return 1.0f - 2.0f * frcp(e + 1.0f);
}

// Single sc0 probe: L1-bypass, serviced from this XCD's L2 (fast when the
// line is local; correctness never depends on it).
__device__ __forceinline__ ull probe_l2(const ull* p) {
  ull v;
  asm volatile("global_load_dwordx2 %0, %1, off sc0\n\ts_waitcnt vmcnt(0)"
               : "=v"(v) : "v"(p) : "memory");
  return v;
}

// R6's SEQUENTIAL dual poll: one sc0 probe, then one agent/LLC probe.
__device__ __forceinline__ float poll_h(const ull* sL2, const ull* sLLC,
                                        int idx, unsigned tag, bool fast) {
  ull v;
  if (fast) {
    for (;;) {
      v = probe_l2(sL2 + idx);                 // fast leg
      if ((unsigned)(v >> 32) == tag) break;
      v = __hip_atomic_load(sLLC + idx, __ATOMIC_RELAXED,
                            __HIP_MEMORY_SCOPE_AGENT);   // correctness leg
      if ((unsigned)(v >> 32) == tag) break;
    }
  } else {
    do {
      v = __hip_atomic_load(sLLC + idx, __ATOMIC_RELAXED,
                            __HIP_MEMORY_SCOPE_AGENT);
    } while ((unsigned)(v >> 32) != tag);
  }
  return __uint_as_float((unsigned)v);
}

__device__ __forceinline__ void publish(ull* sL2, ull* sLLC, int idx, ull pk,
                                        bool fast) {
  if (fast) {
    asm volatile("global_store_dwordx2 %0, %1, off sc0"
                 :: "v"(sL2 + idx), "v"(pk) : "memory");
  }
  __hip_atomic_store(sLLC + idx, pk, __ATOMIC_RELAXED, __HIP_MEMORY_SCOPE_AGENT);
}

__global__ __launch_bounds__(NTHR, 2) void lstm_seq_kernel(
    const float* __restrict__ Whh,
    const float* __restrict__ bih,
    const float* __restrict__ bhh,
    const float* __restrict__ Wo,
    const float* __restrict__ bo,
    float* __restrict__ out,
    ull* sLLC,              // [2][512] device-coherent tagged slots
    ull* sL2,               // [2][512] XCD-L2 tagged slots (sc0 ops)
    int mode)               // 1 = colocated roster + L2 fast leg, 0 = LLC only
{
  // ---- roster: mode 1 -> workers are blockIdx%8==0 (one XCD heuristic) ----
  int r;
  if (mode) {
    if (blockIdx.x & 7) return;       // non-worker: pure dispatch cost
    r = (int)(blockIdx.x >> 3);
  } else {
    r = (int)blockIdx.x;
  }
  if (r >= NWORK) return;
  const bool fast = (mode != 0);

  const int tid = threadIdx.x;
  const int w  = tid >> 6;           // wave id = h column chunk (64 cols)
  const int l  = tid & 63;           // lane = block-local gate-row
  const int g  = l >> 4;             // gate (torch order i,f,g,o)
  const int kk = l & 15;             // k within block
  const int grow = g * HID + r * KPB + kk;

  __shared__ __align__(16) float chbuf[8][64];  // per-wave h chunk (exclusive)
  __shared__ float gpT[2][8][64];    // partials, parity-double-buffered
  __shared__ float hstash[HID];      // h_{r+1} for this block's output row
  __shared__ float vals[4];

  // ---- weights: one 64-col slice of one gate-row per lane (64 VGPRs),
  // overlapped with the bias/h1 prologue (no sync until the s=2 matvec) ----
  float4 wreg[16];
  {
    const float4* Wr = reinterpret_cast<const float4*>(
        Whh + (size_t)grow * HID + w * 64);
#pragma unroll
    for (int j = 0; j < 16; ++j) wreg[j] = Wr[j];
  }

  // ---- h1 = f(bias) locally for THIS thread's h column (k = tid):
  // h0 == 0 kills the recurrent term, so steps 1-2 need no exchange in.
  {
    const float gi = bih[tid]           + bhh[tid];
    const float gf = bih[HID + tid]     + bhh[HID + tid];
    const float gg = bih[2*HID + tid]   + bhh[2*HID + tid];
    const float go = bih[3*HID + tid]   + bhh[3*HID + tid];
    const float c1 = sigm(gf) * 0.0f + sigm(gi) * tanh_f(gg);
    const float h1 = sigm(go) * tanh_f(c1);
    chbuf[w][l] = h1;                // wave-private: no barrier needed
    if (r == 0) hstash[tid] = h1;    // out row 0 uses h1
  }

  // ---- reducer lanes: bias sums + c1 for owned k = r*16+tid ----
  float c_state = 0.0f;
  float bs_i = 0.f, bs_f = 0.f, bs_g = 0.f, bs_o = 0.f;
  if (tid < KPB) {
    const int k = r * KPB + tid;
    bs_i = bih[k]           + bhh[k];
    bs_f = bih[HID + k]     + bhh[HID + k];
    bs_g = bih[2*HID + k]   + bhh[2*HID + k];
    bs_o = bih[3*HID + k]   + bhh[3*HID + k];
    c_state = sigm(bs_f) * 0.0f + sigm(bs_i) * tanh_f(bs_g);
  }

  // ---- steps 2..16: matvec(h_{s-1}) -> reduce -> publish h_s -> stage ----
  for (int s = 2; s <= TSTEPS; ++s) {
    const int p = s & 1;

    float4 a = make_float4(0.f, 0.f, 0.f, 0.f);
    {
      const float4* hq = reinterpret_cast<const float4*>(&chbuf[w][0]);
#pragma unroll
      for (int j = 0; j < 16; ++j) {
        const float4 h4 = hq[j];   // broadcast read: conflict-free
        a.x = fmaf(wreg[j].x, h4.x, a.x);
        a.y = fmaf(wreg[j].y, h4.y, a.y);
        a.z = fmaf(wreg[j].z, h4.z, a.z);
        a.w = fmaf(wreg[j].w, h4.w, a.w);
      }
    }
    gpT[p][w][l] = (a.x + a.y) + (a.z + a.w);
    __syncthreads();   // the only barrier per step

    // reducer lane k: sum 8 chunk-partials per gate, pointwise, publish.
    // Next step's partials go to gpT[p^1] -> no WAR with these reads.
    if (tid < KPB) {
      float p0 = 0.f, p1 = 0.f, p2 = 0.f, p3 = 0.f;
#pragma unroll
      for (int j = 0; j < 8; ++j) {
        p0 += gpT[p][j][tid];
        p1 += gpT[p][j][16 + tid];
        p2 += gpT[p][j][32 + tid];
        p3 += gpT[p][j][48 + tid];
      }
      const float gi = p0 + bs_i, gf = p1 + bs_f;
      const float gg = p2 + bs_g, go = p3 + bs_o;
      c_state = sigm(gf) * c_state + sigm(gi) * tanh_f(gg);
      const float hv = sigm(go) * tanh_f(c_state);
      const ull pk = ((ull)(unsigned)s << 32) | (ull)__float_as_uint(hv);
      publish(sL2, sLLC, p * HID + r * KPB + tid, pk, fast);
    }

    // stage h_s for the next matvec (s<16); capture hstash = h_{r+1} at s==r+1
    if (s < TSTEPS) {
      const float h = poll_h(sL2, sLLC, p * HID + w * 64 + l, (unsigned)s, fast);
      if (r >= 1 && r < OUTB - 1 && s == r + 1) hstash[w * 64 + l] = h;
      chbuf[w][l] = h;   // wave-private; matvec reads of prior value are done
    }
  }

  if (r >= OUTB) return;   // ranks 16..31 only feed the recurrence

  if (r == OUTB - 1) {     // h_16 (tag 16, parity 0) never staged in-loop
    hstash[w * 64 + l] = poll_h(sL2, sLLC, w * 64 + l, (unsigned)TSTEPS, fast);
  }
  __syncthreads();

  // ---- output row t = r: 4 dot products of length 512, then broadcast ----
  if (tid < 256) {
    const int wo = tid >> 6;  // output dim 0..3 (one wave each)
    const int ll = tid & 63;
    float sacc = 0.0f;
#pragma unroll
    for (int j = 0; j < 8; ++j) {
      const int k2 = ll + 64 * j;
      sacc = fmaf(Wo[wo * HID + k2], hstash[k2], sacc);
    }
#pragma unroll
    for (int m = 32; m > 0; m >>= 1) sacc += __shfl_xor(sacc, m);
    if (ll == 0) vals[wo] = sacc + bo[wo];
  }
  __syncthreads();

  const float4 vv = make_float4(vals[0], vals[1], vals[2], vals[3]);
  float4* out4 = reinterpret_cast<float4*>(out) + (size_t)r * 1024;
  out4[tid]       = vv;   // row t=r : 1024 batch rows x 4 floats
  out4[tid + 512] = vv;
}

extern "C" void kernel_launch(void* const* d_in, const int* in_sizes, int n_in,
                              void* d_out, int out_size, void* d_ws, size_t ws_size,
                              hipStream_t stream) {
  // setup_inputs() order:
  // 0 images, 1 W1, 2 b1, 3 W2, 4 b2, 5 W3, 6 b3, 7 We, 8 be,
  // 9 Wih, 10 Whh, 11 bih, 12 bhh, 13 Wg, 14 bg, 15 Wk, 16 bk,
  // 17 Wo, 18 bo, 19 Wc, 20 bc
  const float* Whh = (const float*)d_in[10];
  const float* bih = (const float*)d_in[11];
  const float* bhh = (const float*)d_in[12];
  const float* Wo  = (const float*)d_in[17];
  const float* bo  = (const float*)d_in[18];
  float* out = (float*)d_out;

  // ws layout: 8KB LLC slots | 8KB L2 slots. No reset needed: tagged values
  // are replay-invariant (publishes are deterministic, stale==fresh for
  // matching tags), and 0xAA poison never matches tags 2..16.
  ull* sLLC; ull* sL2; int mode; int grid;
  if (d_ws != nullptr && ws_size >= 4 * HID * sizeof(ull)) {
    sLLC = (ull*)d_ws;
    sL2  = sLLC + 2 * HID;
    mode = 1;
    grid = NWORK * 8;   // workers = blockIdx%8==0 -> one XCD (speed heuristic)
  } else {
    // Out-tail fallback: LLC-only (no sc0 dirty lines over out). Rank-15
    // reads all slots strictly before overwriting this region.
    sLLC = (ull*)(out + (size_t)out_size) - 2 * HID;
    sL2  = sLLC;
    mode = 0;
    grid = NWORK;
  }

  lstm_seq_kernel<<<dim3(grid), dim3(NTHR), 0, stream>>>(
      Whh, bih, bhh, Wo, bo, out, sLLC, sL2, mode);
}